// Round 11
// baseline (29.786 us; speedup 1.0000x reference)
//
#include <hip/hip_runtime.h>
#include <math.h>

// SparseMixer MoE routing: T tokens x 128 experts, top-2.
// R11: R10 (8 waves/SIMD, confirmed 35.4->27.0) + 2-token ILP. R7/R8's
// prefetch failed at 4 waves/SIMD (whole-SIMD convoy); with the convoy fixed,
// per-wave cold-load stalls (~900cy) are now the residual — issue BOTH
// tokens' loads up front so each wave overlaps its own next-token loads.
// Register budget: 2 rows = 32 VGPR + ~25 temps ~= 57 < 64 => still 8 w/SIMD.
// Semantics identical to R8/R10 (passed, absmax 0.002):
//   top-2 first-occurrence tie-break == ref {argmax; -inf; argmax}
//   masked <=> x < theta, theta = v>=0 ? 0.98v : v*(1/0.98)  [v>=x always]
//   s1 = sum_{x>=th1} exp(x-v1); s2 = (sum_{x>=th2} exp(x-v1) - 1)*exp(v1-v2)
// Output (floats): out[0..2T) = indices as float; out[2T..4T) = values.

#define NEXPERTS 128
#define INV098 1.0204082f

__device__ __forceinline__ void process_token(const float4* X, int sub,
                                              int token, float* __restrict__ out,
                                              int T)
{
    // ---- local top-2 over this lane's 16 elements.
    // global e = 4*sub + L, L = 32*c + j; ascending (c,j) == ascending e
    // => first-occurrence tie-break within lane.
    float m1 = -INFINITY, m2 = -INFINITY;
    int   l1 = 0x7fffff, l2 = 0x7fffff;
    #pragma unroll
    for (int c = 0; c < 4; ++c) {
        const float xs[4] = {X[c].x, X[c].y, X[c].z, X[c].w};
        #pragma unroll
        for (int j = 0; j < 4; ++j) {
            const float xv = xs[j];
            const int   L  = 32 * c + j;
            if (xv > m1)      { m2 = m1; l2 = l1; m1 = xv; l1 = L; }
            else if (xv > m2) { m2 = xv; l2 = L; }
        }
    }
    int i1 = 4 * sub + l1;
    int i2 = 4 * sub + l2;

    // ---- 8-lane joint top-2 butterfly (offsets 4,2,1 in-group; ties -> smaller idx)
    #pragma unroll
    for (int off = 4; off > 0; off >>= 1) {
        float om1 = __shfl_xor(m1, off); int oi1 = __shfl_xor(i1, off);
        float om2 = __shfl_xor(m2, off); int oi2 = __shfl_xor(i2, off);
        float w1, ws, lt; int wi1, wis, lti;
        if (om1 > m1 || (om1 == m1 && oi1 < i1)) {
            w1 = om1; wi1 = oi1; ws = om2; wis = oi2; lt = m1;  lti = i1;
        } else {
            w1 = m1;  wi1 = i1;  ws = m2;  wis = i2;  lt = om1; lti = oi1;
        }
        if (lt > ws || (lt == ws && lti < wis)) { m2 = lt; i2 = lti; }
        else                                    { m2 = ws; i2 = wis; }
        m1 = w1; i1 = wi1;
    }
    const float v1 = m1, v2 = m2;

    // ---- theta thresholds: kept_s <=> x >= theta_s
    const float th1 = v1 * (v1 >= 0.f ? 0.98f : INV098);
    const float th2 = v2 * (v2 >= 0.f ? 0.98f : INV098);

    // ---- dual masked sums, one exp per element
    float s1 = 0.f, t2 = 0.f;
    #pragma unroll
    for (int c = 0; c < 4; ++c) {
        const float xs[4] = {X[c].x, X[c].y, X[c].z, X[c].w};
        #pragma unroll
        for (int j = 0; j < 4; ++j) {
            const float xv = xs[j];
            const float ev = __expf(xv - v1);
            if (xv >= th1) s1 += ev;
            if (xv >= th2) t2 += ev;   // includes i1's exp(0)=1
        }
    }
    // ---- 8-lane sum butterfly
    #pragma unroll
    for (int off = 4; off > 0; off >>= 1) {
        s1 += __shfl_xor(s1, off);
        t2 += __shfl_xor(t2, off);
    }

    if (sub == 0) {
        const float s2 = (t2 - 1.0f) * __expf(v1 - v2);  // remove i1, rescale
        out[(size_t)token * 2 + 0] = (float)i1;
        out[(size_t)token * 2 + 1] = (float)i2;
        float* vals = out + (size_t)2 * T;
        vals[(size_t)token * 2 + 0] = 1.0f / s1;
        vals[(size_t)token * 2 + 1] = 1.0f / s2;
    }
}

__global__ __launch_bounds__(256, 8) void sparsemixer_route_kernel(
    const float* __restrict__ logits,
    float* __restrict__ out,
    int T)
{
    const int tid = blockIdx.x * blockDim.x + threadIdx.x;
    const int grp = tid >> 3;                       // 8 lanes per token
    const int sub = threadIdx.x & 7;
    const int G   = (gridDim.x * blockDim.x) >> 3;  // total groups

    const int t0 = grp;
    const int t1 = grp + G;

    // Issue BOTH tokens' loads up front; t1's 4 dwordx4 stay outstanding
    // through t0's compute (each chunk = one full 128B line per group).
    float4 X0[4], X1[4];
    if (t0 < T) {
        const float4* p0 = reinterpret_cast<const float4*>(logits + (size_t)t0 * NEXPERTS);
        #pragma unroll
        for (int c = 0; c < 4; ++c) X0[c] = p0[sub + c * 8];
    }
    if (t1 < T) {
        const float4* p1 = reinterpret_cast<const float4*>(logits + (size_t)t1 * NEXPERTS);
        #pragma unroll
        for (int c = 0; c < 4; ++c) X1[c] = p1[sub + c * 8];
    }

    if (t0 < T) process_token(X0, sub, t0, out, T);
    if (t1 < T) process_token(X1, sub, t1, out, T);
}

extern "C" void kernel_launch(void* const* d_in, const int* in_sizes, int n_in,
                              void* d_out, int out_size, void* d_ws, size_t ws_size,
                              hipStream_t stream) {
    const float* logits = (const float*)d_in[0];
    float* out = (float*)d_out;
    const int T = in_sizes[0] / NEXPERTS;

    // 32 groups/block x 2 tokens/group = 64 tokens per block
    const int blocks = (T + 63) / 64;
    sparsemixer_route_kernel<<<blocks, 256, 0, stream>>>(logits, out, T);
}